// Round 12
// baseline (132.584 us; speedup 1.0000x reference)
//
#include <hip/hip_runtime.h>
#include <hip/hip_bf16.h>

#define D_MODEL 1024
#define INNER   2048
#define NPROJ   4096   // 2*INNER
#define BSZ     2
#define LSEQ    1024
#define MROWS   (BSZ*LSEQ)  // 2048

#define CHUNK 32
#define WARM  24
#define NCHK  (LSEQ / CHUNK)   // 32

using short8   = __attribute__((ext_vector_type(8))) short;
using ushort8  = __attribute__((ext_vector_type(8))) unsigned short;
using f32x4    = __attribute__((ext_vector_type(4))) float;
using f32x16   = __attribute__((ext_vector_type(16))) float;
typedef unsigned short ushort;

#define MFMA32(A,B,Cv) __builtin_amdgcn_mfma_f32_32x32x16_bf16(A,B,Cv,0,0,0)

__device__ __forceinline__ ushort tobf(float x) {
    return (ushort)(__builtin_bit_cast(unsigned, x) >> 16);
}
__device__ __forceinline__ float frombf(ushort h) {
    return __builtin_bit_cast(float, ((unsigned)h) << 16);
}
__device__ __forceinline__ void glds16(const void* g, void* l) {
    __builtin_amdgcn_global_load_lds((const __attribute__((address_space(1))) void*)g,
                                     (__attribute__((address_space(3))) void*)l, 16, 0, 0);
}

// f32 row-major (R x K) -> bf16 hi/lo in 32x16 FRAGMENT-LINEAR subtiles:
// subtile (rt,kt) = 32 rows x 16 cols; lane l = (kchunk<<5)|row holds 8 elems.
template<int K>
__device__ __forceinline__ void split_chunk(const float* __restrict__ in,
                                            ushort* __restrict__ hi,
                                            ushort* __restrict__ lo, int c) {
    int l = c & 63, sub = c >> 6;
    constexpr int KT16 = K / 16;
    int kt = sub % KT16, rt = sub / KT16;
    const float* src = in + (size_t)(rt * 32 + (l & 31)) * K + kt * 16 + (l >> 5) * 8;
    ushort8 h, lw;
#pragma unroll
    for (int j = 0; j < 8; ++j) {
        float x = src[j];
        h[j]  = tobf(x);
        lw[j] = tobf(x - frombf(h[j]));
    }
    *reinterpret_cast<ushort8*>(&hi[(size_t)c * 8]) = h;
    *reinterpret_cast<ushort8*>(&lo[(size_t)c * 8]) = lw;
}

template<int K>
__global__ __launch_bounds__(256) void splitbf_frag(const float* __restrict__ in,
                                                    ushort* __restrict__ hi,
                                                    ushort* __restrict__ lo, int nchunks) {
    int c = blockIdx.x * 256 + threadIdx.x;
    if (c >= nchunks) return;
    split_chunk<K>(in, hi, lo, c);
}

// fused: split two K=1024 matrices (W_in and x) in one launch
__global__ __launch_bounds__(256) void splitbf2_k(
    const float* __restrict__ in1, ushort* __restrict__ hi1, ushort* __restrict__ lo1, int n1,
    const float* __restrict__ in2, ushort* __restrict__ hi2, ushort* __restrict__ lo2, int n2) {
    int c = blockIdx.x * 256 + threadIdx.x;
    if (c < n1) {
        split_chunk<D_MODEL>(in1, hi1, lo1, c);
    } else {
        int cc = c - n1;
        if (cc < n2) split_chunk<D_MODEL>(in2, hi2, lo2, cc);
    }
}

// ---------------------------------------------------------------------------
// Pipelined bf16x3 GEMM (32x32x16): C[MROWS,NCOL] = A[MROWS,K]*B[NCOL,K]^T.
// 512 thr / 8 waves (2Mx4N, wave tile 64x64), BK=32, 3 LDS bufs, 2-tile
// prefetch. ONE barrier per tile. All 16 frag reads issued at tile top in
// pinned groups (ah+bh / bl / al), then 6 glds; counted lgkmcnt(8/4/0)
// between the three MFMA clusters lets reads execute under MFMA; counted
// vmcnt(6) at tile end. WAR-safe: reads of buf[(t+2)%3] (tile t-1) finish
// before BAR(t-1), glds into it issue after BAR(t-1).
// ---------------------------------------------------------------------------
template<int NCOL, int K, int SPLITK, bool PARTIAL, bool RECT>
__global__ __launch_bounds__(512, 1) void gemm_pipe(
    const ushort* __restrict__ Agh, const ushort* __restrict__ Agl,
    const ushort* __restrict__ Bgh, const ushort* __restrict__ Bgl,
    float* __restrict__ C0, float* __restrict__ Crest)
{
    constexpr int KT16 = K / 16;
    constexpr int NT = (K / 32) / SPLITK;         // K-tiles per block
    __shared__ ushort Ah[3][4096], Al[3][4096];   // 128x32 bf16 per buf
    __shared__ ushort Bh[3][8192], Bl[3][8192];   // 256x32 bf16 per buf

    const int tid = threadIdx.x;
    const int wid = tid >> 6, lane = tid & 63;

    constexpr int NTX = NCOL / 256;
    int lin = blockIdx.y * NTX + blockIdx.x;
    int m0, n0;
    if constexpr (RECT) {
        // 16x16 grid: each XCD owns a 4m x 8n rectangle (10 MB operand footprint)
        int xcd = lin & 7, w = lin >> 3;
        m0 = ((xcd & 3) * 4 + (w & 3)) * 128;
        n0 = ((xcd >> 2) * 8 + (w >> 2)) * 256;
    } else {
        constexpr int NXY = NTX * (MROWS / 128);
        constexpr int CPX = NXY / 8;
        int swz = (lin & 7) * CPX + (lin >> 3);
        m0 = (swz / NTX) * 128; n0 = (swz % NTX) * 256;
    }
    const int t0 = (SPLITK > 1 ? blockIdx.z : 0) * NT;
    const int wm = (wid >> 2) * 64, wn = (wid & 3) * 64;

    f32x16 acc[2][2] = {};

    auto issueB = [&](const ushort* __restrict__ src, ushort* dst, int tg, int ci) {
        int s = wid + ci * 8;
        const ushort* g = src +
            ((size_t)((n0 >> 5) + (s >> 1)) * KT16 + 2 * tg + (s & 1)) * 512 + lane * 8;
        glds16(g, dst + s * 512);
    };
    auto issueA = [&](const ushort* __restrict__ src, ushort* dst, int tg) {
        const ushort* g = src +
            ((size_t)((m0 >> 5) + (wid >> 1)) * KT16 + 2 * tg + (wid & 1)) * 512 + lane * 8;
        glds16(g, dst + wid * 512);
    };
    auto stageTile = [&](int t, int b) {
        issueB(Bgh, &Bh[b][0], t0 + t, 0); issueB(Bgh, &Bh[b][0], t0 + t, 1);
        issueB(Bgl, &Bl[b][0], t0 + t, 0); issueB(Bgl, &Bl[b][0], t0 + t, 1);
        issueA(Agh, &Ah[b][0], t0 + t);    issueA(Agl, &Al[b][0], t0 + t);
    };
    const int aoff = (wm >> 5) * 1024 + lane * 8;
    const int boff = (wn >> 5) * 1024 + lane * 8;

    stageTile(0, 0);
    stageTile(1, 1);
    asm volatile("s_waitcnt vmcnt(6)" ::: "memory");
    __builtin_amdgcn_s_barrier();

    int cur = 0;
    for (int t = 0; t < NT; ++t) {
        int nx2 = cur + 2; if (nx2 >= 3) nx2 -= 3;
        const bool pf = (t + 2 < NT);
        short8 ah[4], bh[4], bl[4], al[4];

        // group 1: ah, bh (8 reads)
#pragma unroll
        for (int f = 0; f < 4; ++f) {
            ah[f] = *reinterpret_cast<const short8*>(&Ah[cur][aoff + f * 512]);
            bh[f] = *reinterpret_cast<const short8*>(&Bh[cur][boff + f * 512]);
        }
        __builtin_amdgcn_sched_barrier(0);
        // group 2: bl (4 reads)
#pragma unroll
        for (int f = 0; f < 4; ++f)
            bl[f] = *reinterpret_cast<const short8*>(&Bl[cur][boff + f * 512]);
        __builtin_amdgcn_sched_barrier(0);
        // group 3: al (4 reads)
#pragma unroll
        for (int f = 0; f < 4; ++f)
            al[f] = *reinterpret_cast<const short8*>(&Al[cur][aoff + f * 512]);
        __builtin_amdgcn_sched_barrier(0);
        // prefetch tile t+2 (6 vmcnt ops; do not touch lgkm ds-order)
        if (pf) stageTile(t + 2, nx2);

        asm volatile("s_waitcnt lgkmcnt(8)" ::: "memory");   // ah,bh ready
        __builtin_amdgcn_sched_barrier(0);
        __builtin_amdgcn_s_setprio(1);
#pragma unroll
        for (int i = 0; i < 2; ++i)
#pragma unroll
            for (int j = 0; j < 2; ++j)
#pragma unroll
                for (int ks = 0; ks < 2; ++ks)
                    acc[i][j] = MFMA32(ah[i * 2 + ks], bh[j * 2 + ks], acc[i][j]);
        __builtin_amdgcn_s_setprio(0);

        asm volatile("s_waitcnt lgkmcnt(4)" ::: "memory");   // bl ready
        __builtin_amdgcn_sched_barrier(0);
        __builtin_amdgcn_s_setprio(1);
#pragma unroll
        for (int i = 0; i < 2; ++i)
#pragma unroll
            for (int j = 0; j < 2; ++j)
#pragma unroll
                for (int ks = 0; ks < 2; ++ks)
                    acc[i][j] = MFMA32(ah[i * 2 + ks], bl[j * 2 + ks], acc[i][j]);
        __builtin_amdgcn_s_setprio(0);

        asm volatile("s_waitcnt lgkmcnt(0)" ::: "memory");   // al ready
        __builtin_amdgcn_sched_barrier(0);
        __builtin_amdgcn_s_setprio(1);
#pragma unroll
        for (int i = 0; i < 2; ++i)
#pragma unroll
            for (int j = 0; j < 2; ++j)
#pragma unroll
                for (int ks = 0; ks < 2; ++ks)
                    acc[i][j] = MFMA32(al[i * 2 + ks], bh[j * 2 + ks], acc[i][j]);
        __builtin_amdgcn_s_setprio(0);

        if (pf) asm volatile("s_waitcnt vmcnt(6)" ::: "memory");
        else    asm volatile("s_waitcnt vmcnt(0)" ::: "memory");
        __builtin_amdgcn_s_barrier();   // single barrier per tile
        cur = cur + 1; if (cur == 3) cur = 0;
    }

    float* C = C0;
    if constexpr (PARTIAL) {
        int kz = blockIdx.z;
        if (kz != 0) C = Crest + (size_t)(kz - 1) * MROWS * NCOL;
    }
    // C/D layout (32x32): col = lane&31, row = (r&3) + 8*(r>>2) + 4*(lane>>5)
#pragma unroll
    for (int i = 0; i < 2; ++i)
#pragma unroll
        for (int j = 0; j < 2; ++j)
#pragma unroll
            for (int r = 0; r < 16; ++r) {
                int row = m0 + wm + i * 32 + (r & 3) + 8 * (r >> 2) + 4 * (lane >> 5);
                int col = n0 + wn + j * 32 + (lane & 31);
                C[(size_t)row * NCOL + col] = acc[i][j][r];
            }
}

// out += sum of 3 partials (out already holds partial 0)
__global__ __launch_bounds__(256) void reduce_sk(float* __restrict__ out,
                                                 const float* __restrict__ rest) {
    constexpr size_t MN = (size_t)MROWS * D_MODEL;
    size_t i = ((size_t)blockIdx.x * 256 + threadIdx.x) * 4;
    f32x4 a = *reinterpret_cast<const f32x4*>(&out[i]);
    f32x4 b = *reinterpret_cast<const f32x4*>(&rest[i]);
    f32x4 c = *reinterpret_cast<const f32x4*>(&rest[MN + i]);
    f32x4 d = *reinterpret_cast<const f32x4*>(&rest[2 * MN + i]);
    *reinterpret_cast<f32x4*>(&out[i]) = (a + b) + (c + d);
}

// Chunk-parallel fused conv + sigmoid + scan + gate; emits yg as bf16 hi/lo
// in 32x16 fragment-linear order for GEMM2's A (K = INNER = 2048, KT16 = 128).
__global__ __launch_bounds__(256) void scan_kernel(
    const float* __restrict__ xp,
    const float* __restrict__ conv_w, const float* __restrict__ conv_b,
    const float* __restrict__ Aa, const float* __restrict__ Bp, const float* __restrict__ Cp,
    ushort* __restrict__ yhi, ushort* __restrict__ ylo)
{
    const int NB = INNER / 256;  // 8
    int tid = threadIdx.x;
    int bi = blockIdx.x;
    int b  = bi / (NCHK * NB);
    int r  = bi % (NCHK * NB);
    int ch = r / NB;
    int n  = (r % NB) * 256 + tid;

    float4 w = *reinterpret_cast<const float4*>(&conv_w[n * 4]);
    float cb = conv_b[n];
    float An[16], Bn[16], Cn[16], st[16];
#pragma unroll
    for (int i = 0; i < 16; i += 4) {
        float4 va = *reinterpret_cast<const float4*>(&Aa[n * 16 + i]);
        float4 vb = *reinterpret_cast<const float4*>(&Bp[n * 16 + i]);
        float4 vc = *reinterpret_cast<const float4*>(&Cp[n * 16 + i]);
        An[i]=va.x; An[i+1]=va.y; An[i+2]=va.z; An[i+3]=va.w;
        Bn[i]=vb.x; Bn[i+1]=vb.y; Bn[i+2]=vb.z; Bn[i+3]=vb.w;
        Cn[i]=vc.x; Cn[i+1]=vc.y; Cn[i+2]=vc.z; Cn[i+3]=vc.w;
    }
#pragma unroll
    for (int s = 0; s < 16; ++s) st[s] = 0.f;

    int out0 = ch * CHUNK;
    int lstart = (out0 >= WARM) ? (out0 - WARM) : 0;
    float u0 = 0.f, u1 = 0.f, u2 = 0.f;
    const float* xb = xp + (size_t)b * LSEQ * NPROJ;
    size_t fcol = (size_t)(n >> 4) * 512 + ((n >> 3) & 1) * 256 + (n & 7);

    for (int l = lstart; l < out0; l += 8) {
        float uv[8];
#pragma unroll
        for (int i = 0; i < 8; ++i)
            uv[i] = xb[(size_t)(l + i) * NPROJ + 2 * n];
#pragma unroll
        for (int i = 0; i < 8; ++i) {
            float ul = uv[i];
            float xc = cb + w.x * u0 + w.y * u1 + w.z * u2 + w.w * ul;
            u0 = u1; u1 = u2; u2 = ul;
            float d = 1.f / (1.f + __expf(-xc));
            float dxc = d * xc;
#pragma unroll
            for (int s = 0; s < 16; ++s)
                st[s] = (An[s] * d) * st[s] + Bn[s] * dxc;
        }
    }
    for (int lt = 0; lt < CHUNK; lt += 8) {
        float uv[8], gv[8];
#pragma unroll
        for (int i = 0; i < 8; ++i) {
            float2 ug = *reinterpret_cast<const float2*>(
                &xb[(size_t)(out0 + lt + i) * NPROJ + 2 * n]);
            uv[i] = ug.x; gv[i] = ug.y;
        }
#pragma unroll
        for (int i = 0; i < 8; ++i) {
            float ul = uv[i];
            float xc = cb + w.x * u0 + w.y * u1 + w.z * u2 + w.w * ul;
            u0 = u1; u1 = u2; u2 = ul;
            float d = 1.f / (1.f + __expf(-xc));
            float dxc = d * xc;
            float y0 = 0.f, y1 = 0.f, y2 = 0.f, y3 = 0.f;
#pragma unroll
            for (int s = 0; s < 16; s += 4) {
                st[s + 0] = (An[s + 0] * d) * st[s + 0] + Bn[s + 0] * dxc;
                st[s + 1] = (An[s + 1] * d) * st[s + 1] + Bn[s + 1] * dxc;
                st[s + 2] = (An[s + 2] * d) * st[s + 2] + Bn[s + 2] * dxc;
                st[s + 3] = (An[s + 3] * d) * st[s + 3] + Bn[s + 3] * dxc;
                y0 += st[s + 0] * Cn[s + 0];
                y1 += st[s + 1] * Cn[s + 1];
                y2 += st[s + 2] * Cn[s + 2];
                y3 += st[s + 3] * Cn[s + 3];
            }
            float y = (y0 + y1) + (y2 + y3);
            float g = 1.f / (1.f + __expf(-gv[i]));
            float o = y * g;
            int R = b * LSEQ + out0 + lt + i;
            size_t fi = (size_t)(R >> 5) * (128 * 512) + (R & 31) * 8 + fcol;
            ushort hh = tobf(o);
            yhi[fi] = hh;
            ylo[fi] = tobf(o - frombf(hh));
        }
    }
}

extern "C" void kernel_launch(void* const* d_in, const int* in_sizes, int n_in,
                              void* d_out, int out_size, void* d_ws, size_t ws_size,
                              hipStream_t stream) {
    const float* x      = (const float*)d_in[0];
    const float* W_in   = (const float*)d_in[1];
    const float* conv_w = (const float*)d_in[2];
    const float* conv_b = (const float*)d_in[3];
    const float* A      = (const float*)d_in[4];
    const float* Bp     = (const float*)d_in[5];
    const float* Cp     = (const float*)d_in[6];
    const float* W_out  = (const float*)d_in[8];
    float* out = (float*)d_out;

    char* ws = (char*)d_ws;
    float* xp    = (float*)ws;                       // [0,32M): scan input
    ushort* Whi  = (ushort*)(ws + (32u << 20));      // [32,40M)
    ushort* Wlo  = (ushort*)(ws + (40u << 20));      // [40,48M)
    ushort* yghi = Whi;                              // alias after GEMM1
    ushort* yglo = Wlo;
    ushort* Wohi = (ushort*)ws;                      // [0,4M)  (xp dead after scan)
    ushort* Wolo = (ushort*)(ws + (4u << 20));       // [4,8M)
    float*  Prest = (float*)(ws + (8u << 20));       // [8,32M): split-K partials 1..3
    // x hi/lo live in d_out (8 MB) — consumed by GEMM1, overwritten by GEMM2
    ushort* xhi = (ushort*)d_out;
    ushort* xlo = xhi + (size_t)MROWS * D_MODEL;

    dim3 blk(256);
    const int n1 = NPROJ * D_MODEL / 8;   // 524288
    const int n2 = MROWS * D_MODEL / 8;   // 262144
    splitbf2_k<<<dim3((n1 + n2) / 256), blk, 0, stream>>>(
        W_in, Whi, Wlo, n1, x, xhi, xlo, n2);
    gemm_pipe<NPROJ, D_MODEL, 1, false, true>
        <<<dim3(16, 16), dim3(512), 0, stream>>>(xhi, xlo, Whi, Wlo, xp, nullptr);
    scan_kernel<<<dim3(BSZ * NCHK * (INNER / 256)), blk, 0, stream>>>(
        xp, conv_w, conv_b, A, Bp, Cp, yghi, yglo);
    splitbf_frag<INNER><<<dim3((D_MODEL * INNER / 8) / 256), blk, 0, stream>>>(
        W_out, Wohi, Wolo, D_MODEL * INNER / 8);
    gemm_pipe<D_MODEL, INNER, 4, true, false>
        <<<dim3(4, 16, 4), dim3(512), 0, stream>>>(yghi, yglo, Wohi, Wolo, out, Prest);
    reduce_sk<<<dim3((MROWS * D_MODEL / 4) / 256), blk, 0, stream>>>(out, Prest);
}

// Round 13
// 123.918 us; speedup vs baseline: 1.0699x; 1.0699x over previous
//
#include <hip/hip_runtime.h>
#include <hip/hip_bf16.h>

#define D_MODEL 1024
#define INNER   2048
#define NPROJ   4096   // 2*INNER
#define BSZ     2
#define LSEQ    1024
#define MROWS   (BSZ*LSEQ)  // 2048

#define CHUNK 32
#define WARM  24
#define NCHK  (LSEQ / CHUNK)   // 32

using short8   = __attribute__((ext_vector_type(8))) short;
using ushort8  = __attribute__((ext_vector_type(8))) unsigned short;
using f32x4    = __attribute__((ext_vector_type(4))) float;
typedef unsigned short ushort;

#define MFMA16(A,B,Cv) __builtin_amdgcn_mfma_f32_16x16x32_bf16(A,B,Cv,0,0,0)

__device__ __forceinline__ ushort tobf(float x) {
    return (ushort)(__builtin_bit_cast(unsigned, x) >> 16);
}
__device__ __forceinline__ float frombf(ushort h) {
    return __builtin_bit_cast(float, ((unsigned)h) << 16);
}
__device__ __forceinline__ void glds16(const void* g, void* l) {
    __builtin_amdgcn_global_load_lds((const __attribute__((address_space(1))) void*)g,
                                     (__attribute__((address_space(3))) void*)l, 16, 0, 0);
}

// f32 row-major (R x K) -> bf16 hi/lo in 16x32 FRAGMENT-LINEAR subtiles:
// subtile (rt,kt) = 16 rows x 32 cols; lane l = (kchunk<<4)|row holds 8 elems.
template<int K>
__device__ __forceinline__ void split_chunk(const float* __restrict__ in,
                                            ushort* __restrict__ hi,
                                            ushort* __restrict__ lo, int c) {
    int l = c & 63, sub = c >> 6;
    constexpr int KT = K / 32;
    int kt = sub % KT, rt = sub / KT;
    const float* src = in + (size_t)(rt * 16 + (l & 15)) * K + kt * 32 + (l >> 4) * 8;
    ushort8 h, lw;
#pragma unroll
    for (int j = 0; j < 8; ++j) {
        float x = src[j];
        h[j]  = tobf(x);
        lw[j] = tobf(x - frombf(h[j]));
    }
    *reinterpret_cast<ushort8*>(&hi[(size_t)c * 8]) = h;
    *reinterpret_cast<ushort8*>(&lo[(size_t)c * 8]) = lw;
}

template<int K>
__global__ __launch_bounds__(256) void splitbf_frag(const float* __restrict__ in,
                                                    ushort* __restrict__ hi,
                                                    ushort* __restrict__ lo, int nchunks) {
    int c = blockIdx.x * 256 + threadIdx.x;
    if (c >= nchunks) return;
    split_chunk<K>(in, hi, lo, c);
}

// fused: split two K=1024 matrices (W_in and x) in one launch
__global__ __launch_bounds__(256) void splitbf2_k(
    const float* __restrict__ in1, ushort* __restrict__ hi1, ushort* __restrict__ lo1, int n1,
    const float* __restrict__ in2, ushort* __restrict__ hi2, ushort* __restrict__ lo2, int n2) {
    int c = blockIdx.x * 256 + threadIdx.x;
    if (c < n1) {
        split_chunk<D_MODEL>(in1, hi1, lo1, c);
    } else {
        int cc = c - n1;
        if (cc < n2) split_chunk<D_MODEL>(in2, hi2, lo2, cc);
    }
}

// ---------------------------------------------------------------------------
// Pipelined bf16x3 GEMM (16x16x32): C[MROWS,NCOL] = A[MROWS,K]*B[NCOL,K]^T.
// BM=128 fixed; BN=256 -> 8 waves (2Mx4N), NBUF=3, counted vmcnt(6) (R10);
// BN=128 -> 4 waves (2Mx2N), NBUF=2, vmcnt(0) drain but 64KB LDS -> 2 WGs/CU
// so the drain hides under the co-resident WG's MFMA.
// Per K-tile: R1{MFMA hh; read bl; issue Bh} R2{MFMA hl; read al; issue Bl}
// BAR1 R3{MFMA lh; issue A; vmcnt} BAR2 R4{read next ah,bh}.
// ---------------------------------------------------------------------------
template<int BN, int NCOL, int K, int SPLITK, bool PARTIAL, int NBUF, int NTHR>
__global__ __launch_bounds__(NTHR, 1) void gemm_pipe(
    const ushort* __restrict__ Agh, const ushort* __restrict__ Agl,
    const ushort* __restrict__ Bgh, const ushort* __restrict__ Bgl,
    float* __restrict__ C0, float* __restrict__ Crest)
{
    constexpr int BM = 128;
    constexpr int NW = NTHR / 64;
    constexpr int KT = K / 32;
    constexpr int NT = KT / SPLITK;
    constexpr int CB = (BN / 16) / NW;   // B subtile-loads per wave per matrix
    constexpr int CA = (BM / 16) / NW;   // A subtile-loads per wave per matrix
    __shared__ ushort Ah[NBUF][BM * 32], Al[NBUF][BM * 32];
    __shared__ ushort Bh[NBUF][BN * 32], Bl[NBUF][BN * 32];

    const int tid = threadIdx.x;
    const int wid = tid >> 6, lane = tid & 63;
    const int lm = lane & 15, lk = lane >> 4;

    constexpr int NTX = NCOL / BN;
    constexpr int NXY = NTX * (MROWS / BM);
    constexpr int CPX = NXY / 8;
    int lin = blockIdx.y * NTX + blockIdx.x;
    int swz = (lin & 7) * CPX + (lin >> 3);
    const int m0 = (swz / NTX) * BM, n0 = (swz % NTX) * BN;
    const int t0 = (SPLITK > 1 ? blockIdx.z : 0) * NT;
    const int wm = (NW == 8) ? (wid >> 2) * 64 : (wid >> 1) * 64;
    const int wn = (NW == 8) ? (wid & 3) * 64 : (wid & 1) * 64;

    f32x4 acc[4][4] = {};

    auto issueB = [&](const ushort* __restrict__ src, ushort* dst, int tg) {
#pragma unroll
        for (int ci = 0; ci < CB; ++ci) {
            int s = wid + ci * NW;
            const ushort* g = src + ((size_t)((n0 >> 4) + s) * KT + tg) * 512 + lane * 8;
            glds16(g, dst + s * 512);
        }
    };
    auto issueA = [&](const ushort* __restrict__ src, ushort* dst, int tg) {
#pragma unroll
        for (int ci = 0; ci < CA; ++ci) {
            int s = wid + ci * NW;
            const ushort* g = src + ((size_t)((m0 >> 4) + s) * KT + tg) * 512 + lane * 8;
            glds16(g, dst + s * 512);
        }
    };
    auto stageTile = [&](int t, int b) {
        issueB(Bgh, &Bh[b][0], t0 + t);
        issueB(Bgl, &Bl[b][0], t0 + t);
        issueA(Agh, &Ah[b][0], t0 + t);
        issueA(Agl, &Al[b][0], t0 + t);
    };

    // prologue
    if constexpr (NBUF == 3) {
        stageTile(0, 0);
        stageTile(1, 1);
        asm volatile("s_waitcnt vmcnt(6)" ::: "memory");   // tile 0 landed
    } else {
        stageTile(0, 0);
        asm volatile("s_waitcnt vmcnt(0)" ::: "memory");
    }
    __builtin_amdgcn_s_barrier();

    short8 ah[4], bh[4];
#pragma unroll
    for (int i = 0; i < 4; ++i)
        ah[i] = *reinterpret_cast<const short8*>(&Ah[0][((wm >> 4) + i) * 512 + lane * 8]);
#pragma unroll
    for (int q = 0; q < 4; ++q)
        bh[q] = *reinterpret_cast<const short8*>(&Bh[0][((wn >> 4) + q) * 512 + lane * 8]);

    int cur = 0;
    for (int t = 0; t < NT; ++t) {
        int nxt, stg;
        bool pf;
        if constexpr (NBUF == 3) {
            nxt = cur + 1; if (nxt == 3) nxt = 0;
            stg = cur + 2; if (stg >= 3) stg -= 3;
            pf = (t + 2 < NT);
        } else {
            nxt = cur ^ 1;
            stg = nxt;
            pf = (t + 1 < NT);
        }
        const int tpre = (NBUF == 3) ? t + 2 : t + 1;
        short8 bl[4], al[4];

        // ---- R1: hh MFMA; read bl(cur); issue Bh prefetch ----
        asm volatile("s_waitcnt lgkmcnt(0)" ::: "memory");
        __builtin_amdgcn_sched_barrier(0);
        __builtin_amdgcn_s_setprio(1);
#pragma unroll
        for (int i = 0; i < 4; ++i)
#pragma unroll
            for (int q = 0; q < 4; ++q)
                acc[i][q] = MFMA16(ah[i], bh[q], acc[i][q]);
        __builtin_amdgcn_s_setprio(0);
#pragma unroll
        for (int q = 0; q < 4; ++q)
            bl[q] = *reinterpret_cast<const short8*>(&Bl[cur][((wn >> 4) + q) * 512 + lane * 8]);
        if (pf) issueB(Bgh, &Bh[stg][0], t0 + tpre);

        // ---- R2: hl MFMA; read al(cur); issue Bl prefetch ----
        asm volatile("s_waitcnt lgkmcnt(0)" ::: "memory");
        __builtin_amdgcn_sched_barrier(0);
        __builtin_amdgcn_s_setprio(1);
#pragma unroll
        for (int i = 0; i < 4; ++i)
#pragma unroll
            for (int q = 0; q < 4; ++q)
                acc[i][q] = MFMA16(ah[i], bl[q], acc[i][q]);
        __builtin_amdgcn_s_setprio(0);
#pragma unroll
        for (int i = 0; i < 4; ++i)
            al[i] = *reinterpret_cast<const short8*>(&Al[cur][((wm >> 4) + i) * 512 + lane * 8]);
        if (pf) issueB(Bgl, &Bl[stg][0], t0 + tpre);
        __builtin_amdgcn_s_barrier();   // BAR1

        // ---- R3: lh MFMA; issue A prefetch; counted vmcnt ----
        asm volatile("s_waitcnt lgkmcnt(0)" ::: "memory");
        __builtin_amdgcn_sched_barrier(0);
        __builtin_amdgcn_s_setprio(1);
#pragma unroll
        for (int i = 0; i < 4; ++i)
#pragma unroll
            for (int q = 0; q < 4; ++q)
                acc[i][q] = MFMA16(al[i], bh[q], acc[i][q]);
        __builtin_amdgcn_s_setprio(0);
        if (pf) {
            issueA(Agh, &Ah[stg][0], t0 + tpre);
            issueA(Agl, &Al[stg][0], t0 + tpre);
        }
        if (NBUF == 3 && pf) asm volatile("s_waitcnt vmcnt(6)" ::: "memory");
        else                 asm volatile("s_waitcnt vmcnt(0)" ::: "memory");
        __builtin_amdgcn_s_barrier();   // BAR2: next tile fully staged

        // ---- R4: read next tile's hh frags ----
        if (t + 1 < NT) {
#pragma unroll
            for (int i = 0; i < 4; ++i)
                ah[i] = *reinterpret_cast<const short8*>(&Ah[nxt][((wm >> 4) + i) * 512 + lane * 8]);
#pragma unroll
            for (int q = 0; q < 4; ++q)
                bh[q] = *reinterpret_cast<const short8*>(&Bh[nxt][((wn >> 4) + q) * 512 + lane * 8]);
        }
        cur = nxt;
    }

    float* C = C0;
    if constexpr (PARTIAL) {
        int kz = blockIdx.z;
        if (kz != 0) C = Crest + (size_t)(kz - 1) * MROWS * NCOL;
    }
#pragma unroll
    for (int i = 0; i < 4; ++i)
#pragma unroll
        for (int j = 0; j < 4; ++j)
#pragma unroll
            for (int r = 0; r < 4; ++r) {
                int row = m0 + wm + i * 16 + lk * 4 + r;
                int col = n0 + wn + j * 16 + lm;
                C[(size_t)row * NCOL + col] = acc[i][j][r];
            }
}

// out += sum of 3 partials (out already holds partial 0)
__global__ __launch_bounds__(256) void reduce_sk(float* __restrict__ out,
                                                 const float* __restrict__ rest) {
    constexpr size_t MN = (size_t)MROWS * D_MODEL;
    size_t i = ((size_t)blockIdx.x * 256 + threadIdx.x) * 4;
    f32x4 a = *reinterpret_cast<const f32x4*>(&out[i]);
    f32x4 b = *reinterpret_cast<const f32x4*>(&rest[i]);
    f32x4 c = *reinterpret_cast<const f32x4*>(&rest[MN + i]);
    f32x4 d = *reinterpret_cast<const f32x4*>(&rest[2 * MN + i]);
    *reinterpret_cast<f32x4*>(&out[i]) = (a + b) + (c + d);
}

// Chunk-parallel fused conv + sigmoid + scan + gate; emits yg as bf16 hi/lo
// in 16x32 fragment-linear order for GEMM2's A (K = INNER = 2048, KT = 64).
__global__ __launch_bounds__(256) void scan_kernel(
    const float* __restrict__ xp,
    const float* __restrict__ conv_w, const float* __restrict__ conv_b,
    const float* __restrict__ Aa, const float* __restrict__ Bp, const float* __restrict__ Cp,
    ushort* __restrict__ yhi, ushort* __restrict__ ylo)
{
    const int NB = INNER / 256;  // 8
    int tid = threadIdx.x;
    int bi = blockIdx.x;
    int b  = bi / (NCHK * NB);
    int r  = bi % (NCHK * NB);
    int ch = r / NB;
    int n  = (r % NB) * 256 + tid;

    float4 w = *reinterpret_cast<const float4*>(&conv_w[n * 4]);
    float cb = conv_b[n];
    float An[16], Bn[16], Cn[16], st[16];
#pragma unroll
    for (int i = 0; i < 16; i += 4) {
        float4 va = *reinterpret_cast<const float4*>(&Aa[n * 16 + i]);
        float4 vb = *reinterpret_cast<const float4*>(&Bp[n * 16 + i]);
        float4 vc = *reinterpret_cast<const float4*>(&Cp[n * 16 + i]);
        An[i]=va.x; An[i+1]=va.y; An[i+2]=va.z; An[i+3]=va.w;
        Bn[i]=vb.x; Bn[i+1]=vb.y; Bn[i+2]=vb.z; Bn[i+3]=vb.w;
        Cn[i]=vc.x; Cn[i+1]=vc.y; Cn[i+2]=vc.z; Cn[i+3]=vc.w;
    }
#pragma unroll
    for (int s = 0; s < 16; ++s) st[s] = 0.f;

    int out0 = ch * CHUNK;
    int lstart = (out0 >= WARM) ? (out0 - WARM) : 0;
    float u0 = 0.f, u1 = 0.f, u2 = 0.f;
    const float* xb = xp + (size_t)b * LSEQ * NPROJ;
    size_t fcol = (size_t)(n >> 5) * 512 + ((n >> 3) & 3) * 128 + (n & 7);

    for (int l = lstart; l < out0; l += 8) {
        float uv[8];
#pragma unroll
        for (int i = 0; i < 8; ++i)
            uv[i] = xb[(size_t)(l + i) * NPROJ + 2 * n];
#pragma unroll
        for (int i = 0; i < 8; ++i) {
            float ul = uv[i];
            float xc = cb + w.x * u0 + w.y * u1 + w.z * u2 + w.w * ul;
            u0 = u1; u1 = u2; u2 = ul;
            float d = 1.f / (1.f + __expf(-xc));
            float dxc = d * xc;
#pragma unroll
            for (int s = 0; s < 16; ++s)
                st[s] = (An[s] * d) * st[s] + Bn[s] * dxc;
        }
    }
    for (int lt = 0; lt < CHUNK; lt += 8) {
        float uv[8], gv[8];
#pragma unroll
        for (int i = 0; i < 8; ++i) {
            float2 ug = *reinterpret_cast<const float2*>(
                &xb[(size_t)(out0 + lt + i) * NPROJ + 2 * n]);
            uv[i] = ug.x; gv[i] = ug.y;
        }
#pragma unroll
        for (int i = 0; i < 8; ++i) {
            float ul = uv[i];
            float xc = cb + w.x * u0 + w.y * u1 + w.z * u2 + w.w * ul;
            u0 = u1; u1 = u2; u2 = ul;
            float d = 1.f / (1.f + __expf(-xc));
            float dxc = d * xc;
            float y0 = 0.f, y1 = 0.f, y2 = 0.f, y3 = 0.f;
#pragma unroll
            for (int s = 0; s < 16; s += 4) {
                st[s + 0] = (An[s + 0] * d) * st[s + 0] + Bn[s + 0] * dxc;
                st[s + 1] = (An[s + 1] * d) * st[s + 1] + Bn[s + 1] * dxc;
                st[s + 2] = (An[s + 2] * d) * st[s + 2] + Bn[s + 2] * dxc;
                st[s + 3] = (An[s + 3] * d) * st[s + 3] + Bn[s + 3] * dxc;
                y0 += st[s + 0] * Cn[s + 0];
                y1 += st[s + 1] * Cn[s + 1];
                y2 += st[s + 2] * Cn[s + 2];
                y3 += st[s + 3] * Cn[s + 3];
            }
            float y = (y0 + y1) + (y2 + y3);
            float g = 1.f / (1.f + __expf(-gv[i]));
            float o = y * g;
            int R = b * LSEQ + out0 + lt + i;
            size_t fi = ((size_t)(R >> 4) * 64) * 512 + fcol + (R & 15) * 8;
            ushort hh = tobf(o);
            yhi[fi] = hh;
            ylo[fi] = tobf(o - frombf(hh));
        }
    }
}

extern "C" void kernel_launch(void* const* d_in, const int* in_sizes, int n_in,
                              void* d_out, int out_size, void* d_ws, size_t ws_size,
                              hipStream_t stream) {
    const float* x      = (const float*)d_in[0];
    const float* W_in   = (const float*)d_in[1];
    const float* conv_w = (const float*)d_in[2];
    const float* conv_b = (const float*)d_in[3];
    const float* A      = (const float*)d_in[4];
    const float* Bp     = (const float*)d_in[5];
    const float* Cp     = (const float*)d_in[6];
    const float* W_out  = (const float*)d_in[8];
    float* out = (float*)d_out;

    char* ws = (char*)d_ws;
    float* xp    = (float*)ws;                       // [0,32M): scan input
    ushort* Whi  = (ushort*)(ws + (32u << 20));      // [32,40M)
    ushort* Wlo  = (ushort*)(ws + (40u << 20));      // [40,48M)
    ushort* yghi = Whi;                              // alias after GEMM1
    ushort* yglo = Wlo;
    ushort* Wohi = (ushort*)ws;                      // [0,4M)  (xp dead after scan)
    ushort* Wolo = (ushort*)(ws + (4u << 20));       // [4,8M)
    float*  Prest = (float*)(ws + (8u << 20));       // [8,32M): split-K partials 1..3
    // x hi/lo live in d_out (8 MB) — consumed by GEMM1, overwritten by GEMM2
    ushort* xhi = (ushort*)d_out;
    ushort* xlo = xhi + (size_t)MROWS * D_MODEL;

    dim3 blk(256);
    const int n1 = NPROJ * D_MODEL / 8;   // 524288
    const int n2 = MROWS * D_MODEL / 8;   // 262144
    splitbf2_k<<<dim3((n1 + n2) / 256), blk, 0, stream>>>(
        W_in, Whi, Wlo, n1, x, xhi, xlo, n2);
    gemm_pipe<256, NPROJ, D_MODEL, 1, false, 3, 512>
        <<<dim3(16, 16), dim3(512), 0, stream>>>(xhi, xlo, Whi, Wlo, xp, nullptr);
    scan_kernel<<<dim3(BSZ * NCHK * (INNER / 256)), blk, 0, stream>>>(
        xp, conv_w, conv_b, A, Bp, Cp, yghi, yglo);
    splitbf_frag<INNER><<<dim3((D_MODEL * INNER / 8) / 256), blk, 0, stream>>>(
        W_out, Wohi, Wolo, D_MODEL * INNER / 8);
    gemm_pipe<128, D_MODEL, INNER, 4, true, 2, 256>
        <<<dim3(8, 16, 4), dim3(256), 0, stream>>>(yghi, yglo, Wohi, Wolo, out, Prest);
    reduce_sk<<<dim3((MROWS * D_MODEL / 4) / 256), blk, 0, stream>>>(out, Prest);
}